// Round 6
// baseline (298.567 us; speedup 1.0000x reference)
//
#include <hip/hip_runtime.h>
#include <hip/hip_bf16.h>
#include <math.h>

typedef __bf16 bf16_t;
typedef __bf16 bf16x2 __attribute__((ext_vector_type(2)));
typedef __bf16 bf16x4 __attribute__((ext_vector_type(4)));
typedef __bf16 bf16x8 __attribute__((ext_vector_type(8)));
typedef float floatx4 __attribute__((ext_vector_type(4)));
typedef unsigned short ushort4v __attribute__((ext_vector_type(4)));

#define AS1 __attribute__((address_space(1)))
#define AS3 __attribute__((address_space(3)))

// Problem constants
#define BB 4
#define SS 2048
#define DD 1024
#define HH 16
#define DH 64
#define MM (BB * SS)          // 8192

__device__ __forceinline__ void gld_lds16(const bf16_t* g, bf16_t* l) {
    __builtin_amdgcn_global_load_lds((const AS1 void*)g, (AS3 void*)l, 16, 0, 0);
}

// ---------------------------------------------------------------------------
// Fused preprocessing: ONE kernel replaces detect_dtype + convert_x +
// 2x transpose_cvt + 2x convert1d (6 launches -> 1; ~10us launch gap each).
// Every block re-derives the dtype flag from x's first 128 ushorts (L2-hot)
// via a wave-0 ballot -- no cross-kernel dependency.
// Sections by blockIdx.x:
//   [0,8192)        convert_x   (1024 elems/block)
//   [8192,11264)    w_in  transpose  (96 x 32 tiles)
//   [11264,12288)   w_out transpose  (32 x 32 tiles)
//   [12288,12300)   b_in  convert    (12 blocks)
//   [12300,12304)   b_out convert    (4 blocks)
// ---------------------------------------------------------------------------
__global__ __launch_bounds__(256)
void prep(const void* __restrict__ x_raw, bf16_t* __restrict__ xc,
          const void* __restrict__ w_in_raw, bf16_t* __restrict__ w_in_t,
          const void* __restrict__ w_out_raw, bf16_t* __restrict__ w_out_t,
          const void* __restrict__ b_in_raw, bf16_t* __restrict__ b_in_c,
          const void* __restrict__ b_out_raw, bf16_t* __restrict__ b_out_c) {
    __shared__ bf16_t tile[32][33];
    __shared__ int sflag;
    const int tid = threadIdx.x;

    // local dtype detect (fp32 -> flag=1): same rule as original detect_dtype
    if (tid < 64) {
        const unsigned short* xs = (const unsigned short*)x_raw;
        int e0 = (xs[tid * 2] >> 7) & 0xFF;
        int e1 = (xs[tid * 2 + 1] >> 7) & 0xFF;
        int h = (e0 >= 144 ? 1 : 0) + (e1 >= 144 ? 1 : 0);
#pragma unroll
        for (int off = 1; off < 64; off <<= 1) h += __shfl_xor(h, off);
        if (tid == 0) sflag = (h >= 4) ? 1 : 0;
    }
    __syncthreads();
    const int flag = sflag;

    const int bid = blockIdx.x;
    if (bid < 8192) {
        // ---- convert_x ----
        const int i4 = (bid * 256 + tid) * 4;
        if (flag) {
            floatx4 v = ((const floatx4*)x_raw)[i4 >> 2];
            xc[i4 + 0] = (bf16_t)v[0];
            xc[i4 + 1] = (bf16_t)v[1];
            xc[i4 + 2] = (bf16_t)v[2];
            xc[i4 + 3] = (bf16_t)v[3];
        } else {
            ((ushort4v*)xc)[i4 >> 2] = ((const ushort4v*)x_raw)[i4 >> 2];
        }
    } else if (bid < 12288) {
        // ---- transpose_cvt (w_in or w_out) ----
        const void* in;
        bf16_t* out;
        int R, C, idx;
        if (bid < 11264) { in = w_in_raw; out = w_in_t; R = DD; C = 3 * DD; idx = bid - 8192; }
        else             { in = w_out_raw; out = w_out_t; R = DD; C = DD;   idx = bid - 11264; }
        const int nbx = C / 32;
        const int c0 = (idx % nbx) * 32;
        const int r0 = (idx / nbx) * 32;
        const int tx = tid & 31;
        const int ty = tid >> 5;
        if (flag) {
            const float* fin = (const float*)in;
#pragma unroll
            for (int i = 0; i < 32; i += 8)
                tile[ty + i][tx] = (bf16_t)fin[(size_t)(r0 + ty + i) * C + (c0 + tx)];
        } else {
            const bf16_t* bin = (const bf16_t*)in;
#pragma unroll
            for (int i = 0; i < 32; i += 8)
                tile[ty + i][tx] = bin[(size_t)(r0 + ty + i) * C + (c0 + tx)];
        }
        __syncthreads();
#pragma unroll
        for (int i = 0; i < 32; i += 8)
            out[(size_t)(c0 + ty + i) * R + (r0 + tx)] = tile[tx][ty + i];
    } else {
        // ---- bias converts ----
        const void* in;
        bf16_t* out;
        int i;
        if (bid < 12300) { in = b_in_raw; out = b_in_c; i = (bid - 12288) * 256 + tid; }
        else             { in = b_out_raw; out = b_out_c; i = (bid - 12300) * 256 + tid; }
        out[i] = flag ? (bf16_t)((const float*)in)[i] : ((const bf16_t*)in)[i];
    }
}

// ---------------------------------------------------------------------------
// 128x256 bf16 MFMA GEMM, BK=64, 8 waves (2M x 4N, 64x64 per wave).
// Zero-tail grids: gemm0 = 64x12 = 768 = 3x256 CUs; gemm1 = 64x4 = 256.
// r5-proven cadence (see ring/WAR audit in r5 notes) + T5 setprio around
// MFMA clusters (structure-conditional: applies to phase-split schedules,
// m218b/m224 +21-39%; m190's null was the non-phase-split structure).
// MODE 0: qkv scatter epilogue (q bf16, k fp32+bf16, v fp32+v_t bf16).
// MODE 1: plain fp32 out.
// ---------------------------------------------------------------------------
#define MFMA8(I, AF)                                                           \
    do {                                                                       \
        __builtin_amdgcn_s_setprio(1);                                         \
        _Pragma("unroll")                                                      \
        for (int n = 0; n < 4; ++n) {                                          \
            acc[I][n] = __builtin_amdgcn_mfma_f32_16x16x32_bf16(               \
                AF[0], bfr[n][0], acc[I][n], 0, 0, 0);                         \
            acc[I][n] = __builtin_amdgcn_mfma_f32_16x16x32_bf16(               \
                AF[1], bfr[n][1], acc[I][n], 0, 0, 0);                         \
        }                                                                      \
        __builtin_amdgcn_s_setprio(0);                                         \
    } while (0)

template <int MODE>
__global__ __launch_bounds__(512, 2)
void gemm256(const bf16_t* __restrict__ A, const bf16_t* __restrict__ Bt,
             const bf16_t* __restrict__ bias,
             bf16_t* __restrict__ qout, float* __restrict__ kf,
             bf16_t* __restrict__ kb, bf16_t* __restrict__ vtp,
             float* __restrict__ vf, float* __restrict__ outf,
             int nbx, int N) {
    constexpr int KK = 1024;
    constexpr int NT = KK / 64;              // 16 K-tiles
    __shared__ bf16_t Ah[4][64 * 64];        // 32 KB
    __shared__ bf16_t Bh[4][128 * 64];       // 64 KB
    const int tid = threadIdx.x;
    const int w = tid >> 6;
    const int l = tid & 63;
    const int quad = l >> 4;
    const int l16 = l & 15;
    const int wm = w & 1;                    // 2 wave-rows (64 M-rows each)
    const int wn = w >> 1;                   // 4 wave-cols (64 N-cols each)

    // XCD-bijective swizzle (gridDim.x % 8 == 0)
    const int cpx = gridDim.x >> 3;
    const int wg = (blockIdx.x & 7) * cpx + (blockIdx.x >> 3);
    const int m0 = (wg / nbx) * 128;
    const int n0 = (wg % nbx) * 256;

    // staging: row = half*64 + (tid>>3); source granule pre-swizzled so
    // LDS[row][g] = global[row][g ^ (row&7)]
    const int srow = tid >> 3;               // 0..63
    const int sg = (tid & 7) ^ (srow & 7);
    const bf16_t* ag = A + (size_t)(m0 + srow) * KK + sg * 8;
    const bf16_t* bg = Bt + (size_t)(n0 + srow) * KK + sg * 8;
    const int dst0 = w * 512;                // wave-uniform LDS base (elems)

    auto stA = [&](int u, int half) {        // 64x64 half: 1 load/thread
        gld_lds16(ag + (size_t)half * 64 * KK + u * 64,
                  &Ah[(2 * u + half) & 3][dst0]);
    };
    auto stB = [&](int u, int half) {        // 128x64 half: 2 loads/thread
        const bf16_t* g = bg + (size_t)half * 128 * KK + u * 64;
        bf16_t* s = &Bh[(2 * u + half) & 3][dst0];
        gld_lds16(g, s);
        gld_lds16(g + (size_t)64 * KK, s + 4096);
    };

    const int axor = l16 & 7;                // row&7 for all frag reads
    auto rdA = [&](int slot, int mt, int kh) -> bf16x8 {
        return *(const bf16x8*)&Ah[slot][(mt * 16 + l16) * 64 +
                                         ((((kh << 2) | quad) ^ axor) << 3)];
    };
    auto rdB = [&](int slot, int nt, int kh) -> bf16x8 {
        return *(const bf16x8*)&Bh[slot][((wn & 1) * 64 + nt * 16 + l16) * 64 +
                                         ((((kh << 2) | quad) ^ axor) << 3)];
    };

    floatx4 acc[4][4];
#pragma unroll
    for (int i = 0; i < 4; ++i)
#pragma unroll
        for (int j = 0; j < 4; ++j) {
            floatx4 z = {0.f, 0.f, 0.f, 0.f};
            acc[i][j] = z;
        }

    bf16x8 bfr[4][2], a0[2], a1[2], a2[2], a3[2];

    // prologue: B(0)x4, A(0)x2, B(1)x4; demand A(0)+B(0) (oldest 6)
    stB(0, 0); stB(0, 1); stA(0, 0); stA(0, 1); stB(1, 0); stB(1, 1);
    asm volatile("s_waitcnt vmcnt(4)" ::: "memory");
    __builtin_amdgcn_s_barrier();

    for (int u = 0; u < NT; ++u) {
        const int sa = (2 * u + wm) & 3;
        const int sb = (2 * u + (wn >> 1)) & 3;
        // ---- p0 ----
        if (u + 1 < NT) { stA(u + 1, 0); stA(u + 1, 1); }
        __builtin_amdgcn_s_barrier();
#pragma unroll
        for (int n = 0; n < 4; ++n) {
            bfr[n][0] = rdB(sb, n, 0);
            bfr[n][1] = rdB(sb, n, 1);
        }
        a0[0] = rdA(sa, 0, 0); a0[1] = rdA(sa, 0, 1);
        MFMA8(0, a0);
        // ---- p1 ----
        __builtin_amdgcn_s_barrier();
        a1[0] = rdA(sa, 1, 0); a1[1] = rdA(sa, 1, 1);
        MFMA8(1, a1);
        // ---- p2 ----
        if (u + 2 < NT) stB(u + 2, 0);
        __builtin_amdgcn_s_barrier();
        a2[0] = rdA(sa, 2, 0); a2[1] = rdA(sa, 2, 1);
        a3[0] = rdA(sa, 3, 0); a3[1] = rdA(sa, 3, 1);
        MFMA8(2, a2);
        // ---- p3 ----
        if (u + 2 < NT) stB(u + 2, 1);
        if (u + 1 < NT) {
            if (u + 2 < NT) asm volatile("s_waitcnt vmcnt(4)" ::: "memory");
            else            asm volatile("s_waitcnt vmcnt(0)" ::: "memory");
        }
        __builtin_amdgcn_s_barrier();
        MFMA8(3, a3);
    }

    // ---------------- epilogue ----------------
    // C row = m0 + wm*64 + mt*16 + quad*4 + r ; col = n0 + wn*64 + nt*16 + l16
    const int nb = n0 + wn * 64;
    const int mrow0 = m0 + wm * 64;
    float bv[4];
#pragma unroll
    for (int nt = 0; nt < 4; ++nt) bv[nt] = (float)bias[nb + nt * 16 + l16];

    if (MODE == 0) {
        const int sec = nb >> 10;            // wave-uniform: 0=q 1=k 2=v
        const int c = nb & 1023;
        const int hh = c >> 6;
        const int b = mrow0 >> 11;
        const int sb0 = mrow0 & 2047;
        if (sec == 2) {
#pragma unroll
            for (int mt = 0; mt < 4; ++mt)
#pragma unroll
                for (int nt = 0; nt < 4; ++nt) {
                    const int dcol = nt * 16 + l16;
                    const int sbase = sb0 + mt * 16 + quad * 4;
                    bf16x4 pk;
#pragma unroll
                    for (int r = 0; r < 4; ++r) {
                        const float val = acc[mt][nt][r] + bv[nt];
                        pk[r] = (bf16_t)val;
                        vf[((size_t)(b * HH + hh) * SS + sbase + r) * DH + dcol] = val;
                    }
                    *(bf16x4*)&vtp[((size_t)(b * HH + hh) * DH + dcol) * SS + sbase] = pk;
                }
        } else if (sec == 0) {
#pragma unroll
            for (int mt = 0; mt < 4; ++mt)
#pragma unroll
                for (int nt = 0; nt < 4; ++nt) {
                    const int dcol = nt * 16 + l16;
#pragma unroll
                    for (int r = 0; r < 4; ++r) {
                        const int s = sb0 + mt * 16 + quad * 4 + r;
                        qout[((size_t)(b * HH + hh) * SS + s) * DH + dcol] =
                            (bf16_t)(acc[mt][nt][r] + bv[nt]);
                    }
                }
        } else {
#pragma unroll
            for (int mt = 0; mt < 4; ++mt)
#pragma unroll
                for (int nt = 0; nt < 4; ++nt) {
                    const int dcol = nt * 16 + l16;
#pragma unroll
                    for (int r = 0; r < 4; ++r) {
                        const int s = sb0 + mt * 16 + quad * 4 + r;
                        const size_t di = ((size_t)(b * HH + hh) * SS + s) * DH + dcol;
                        const float val = acc[mt][nt][r] + bv[nt];
                        kf[di] = val;
                        kb[di] = (bf16_t)val;
                    }
                }
        }
    } else {
#pragma unroll
        for (int mt = 0; mt < 4; ++mt)
#pragma unroll
            for (int nt = 0; nt < 4; ++nt)
#pragma unroll
                for (int r = 0; r < 4; ++r) {
                    const int m = mrow0 + mt * 16 + quad * 4 + r;
                    outf[(size_t)m * N + nb + nt * 16 + l16] = acc[mt][nt][r] + bv[nt];
                }
    }
}
#undef MFMA8

// ---------------------------------------------------------------------------
// Flash v5: K/V staged to LDS via global_load_lds, K double-buffered,
// XOR-swizzled reads, fixed-base softmax, XCD-pinned grid.
// + T5 setprio around QK/PV MFMA clusters (m191: +4-7% on attn).
// ---------------------------------------------------------------------------
#define PST 72   // Ps row stride (bf16 elems): 144 B -> conflict-light

// stage a 64-row x 128B tile into LDS (linear layout, source pre-swizzled)
__device__ __forceinline__ void stage_kv(const bf16_t* __restrict__ g, int rstride_e,
                                         bf16_t* l, int tid, int wave) {
#pragma unroll
    for (int half = 0; half < 2; ++half) {
        const int row = half * 32 + (tid >> 3);
        const int srcslot = (tid & 7) ^ (row & 7);
        gld_lds16(g + (size_t)row * rstride_e + srcslot * 8,
                  l + half * 2048 + wave * 512);
    }
}

// swizzled b128 fragment read: logical (row, 16B-slot s)
__device__ __forceinline__ bf16x8 ldsfrag(const bf16_t* base, int row, int s) {
    return *(const bf16x8*)&base[row * 64 + ((s ^ (row & 7)) << 3)];
}

__global__ __launch_bounds__(256)
void flash_v5(const bf16_t* __restrict__ q, const bf16_t* __restrict__ kbf,
              const bf16_t* __restrict__ vt, bf16_t* __restrict__ ao) {
    __shared__ bf16_t Ks[2][64 * 64];        // 2 x 8 KB
    __shared__ bf16_t Vs[64 * 64];           // 8 KB
    __shared__ bf16_t Ps[4][16 * PST];       // 9 KB
    const int tid = threadIdx.x;
    const int wave = tid >> 6;
    const int lane = tid & 63;
    const int quad = lane >> 4;
    const int l16 = lane & 15;

    // XCD-pinned decomposition of 2048 blocks (longest q-tiles first)
    const int linear = blockIdx.x;
    const int xcd = linear & 7;
    const int sl = linear >> 3;          // 0..255
    const int hi = sl & 7;               // head-within-XCD
    const int qt = 31 - (sl >> 3);       // longest first
    const int bh = xcd * 8 + hi;
    const int r0 = qt * 64 + wave * 16;
    const int b = bh >> 4;
    const int h = bh & 15;

    const bf16_t* qp = q + (size_t)bh * SS * DH;
    const bf16_t* kp = kbf + (size_t)bh * SS * DH;
    const bf16_t* vp = vt + (size_t)bh * DH * SS;
    bf16_t* ps = Ps[wave];

    // Q A-frags: A[m=l16][k=quad*8+j]
    bf16x8 aq0, aq1;
    {
        const bf16_t* qr = qp + (size_t)(r0 + l16) * DH + quad * 8;
        aq0 = *(const bf16x8*)qr;
        aq1 = *(const bf16x8*)(qr + 32);
    }

    floatx4 o[4];
#pragma unroll
    for (int nt = 0; nt < 4; ++nt) {
        floatx4 z = {0.f, 0.f, 0.f, 0.f};
        o[nt] = z;
    }
    float lrow[4] = {0.f, 0.f, 0.f, 0.f};

    const float c2 = 0.18033688011112042f;   // (1/sqrt(64)) * log2(e)
    const float FB = 16.0f;                  // fixed softmax base (|s*c2|<~10)
    const int nIter = qt + 1;                // j0 = 0 .. qt*64

    // prologue: stage K(0)
    stage_kv(kp, DH, Ks[0], tid, wave);
    asm volatile("s_waitcnt vmcnt(0)" ::: "memory");
    __builtin_amdgcn_s_barrier();

    int cur = 0;
    for (int it = 0; it < nIter; ++it) {
        const int j0 = it * 64;
        // issue V(j0) and K(j0+64) stages; latency covered by scores+softmax
        stage_kv(vp + j0, SS, Vs, tid, wave);
        if (it + 1 < nIter)
            stage_kv(kp + (size_t)(j0 + 64) * DH, DH, Ks[cur ^ 1], tid, wave);

        // scores from Ks[cur] (ready: barrier at end of prev iter / prologue)
        const bf16_t* Kc = Ks[cur];
        floatx4 sc[4];
        __builtin_amdgcn_s_setprio(1);
#pragma unroll
        for (int cp = 0; cp < 4; ++cp) {
            const int krow = (cp >> 1) * 32 + 2 * l16 + (cp & 1);
            const bf16x8 kf0 = ldsfrag(Kc, krow, quad);
            const bf16x8 kf1 = ldsfrag(Kc, krow, 4 + quad);
            floatx4 z = {0.f, 0.f, 0.f, 0.f};
            z = __builtin_amdgcn_mfma_f32_16x16x32_bf16(aq0, kf0, z, 0, 0, 0);
            z = __builtin_amdgcn_mfma_f32_16x16x32_bf16(aq1, kf1, z, 0, 0, 0);
            sc[cp] = z;
        }
        __builtin_amdgcn_s_setprio(0);

        // probs: p = exp2(s*c2 - FB); mask only on diagonal tile (wave-uniform)
        if (it == nIter - 1) {
#pragma unroll
            for (int r = 0; r < 4; ++r) {
                const int qi = r0 + quad * 4 + r;
                float p[4];
#pragma unroll
                for (int cp = 0; cp < 4; ++cp) {
                    const int key = j0 + (cp >> 1) * 32 + 2 * l16 + (cp & 1);
                    const float e = __builtin_amdgcn_exp2f(fmaf(sc[cp][r], c2, -FB));
                    p[cp] = (key <= qi) ? e : 0.f;
                }
                lrow[r] += (p[0] + p[1]) + (p[2] + p[3]);
                const int qrow = quad * 4 + r;
                bf16x2 w0, w1;
                w0[0] = (bf16_t)p[0]; w0[1] = (bf16_t)p[1];
                w1[0] = (bf16_t)p[2]; w1[1] = (bf16_t)p[3];
                *(bf16x2*)&ps[qrow * PST + 2 * l16] = w0;
                *(bf16x2*)&ps[qrow * PST + 32 + 2 * l16] = w1;
            }
        } else {
#pragma unroll
            for (int r = 0; r < 4; ++r) {
                float p[4];
#pragma unroll
                for (int cp = 0; cp < 4; ++cp)
                    p[cp] = __builtin_amdgcn_exp2f(fmaf(sc[cp][r], c2, -FB));
                lrow[r] += (p[0] + p[1]) + (p[2] + p[3]);
                const int qrow = quad * 4 + r;
                bf16x2 w0, w1;
                w0[0] = (bf16_t)p[0]; w0[1] = (bf16_t)p[1];
                w1[0] = (bf16_t)p[2]; w1[1] = (bf16_t)p[3];
                *(bf16x2*)&ps[qrow * PST + 2 * l16] = w0;
                *(bf16x2*)&ps[qrow * PST + 32 + 2 * l16] = w1;
            }
        }
        asm volatile("s_waitcnt lgkmcnt(0)" ::: "memory");   // wave-local Ps w->r
        bf16x8 ap0 = *(const bf16x8*)&ps[l16 * PST + quad * 8];
        bf16x8 ap1 = *(const bf16x8*)&ps[l16 * PST + 32 + quad * 8];

        // V(j0) + K(j0+64) landed (issued together at iter top); cross-wave sync
        asm volatile("s_waitcnt vmcnt(0) lgkmcnt(0)" ::: "memory");
        __builtin_amdgcn_s_barrier();

        __builtin_amdgcn_s_setprio(1);
#pragma unroll
        for (int nt = 0; nt < 4; ++nt) {
            const int vrow = nt * 16 + l16;
            const bf16x8 vf0 = ldsfrag(Vs, vrow, quad);
            const bf16x8 vf1 = ldsfrag(Vs, vrow, 4 + quad);
            o[nt] = __builtin_amdgcn_mfma_f32_16x16x32_bf16(ap0, vf0, o[nt], 0, 0, 0);
            o[nt] = __builtin_amdgcn_mfma_f32_16x16x32_bf16(ap1, vf1, o[nt], 0, 0, 0);
        }
        __builtin_amdgcn_s_setprio(0);

        // all waves done reading Vs / Ks[cur] before next-iter overwrite
        asm volatile("s_waitcnt lgkmcnt(0)" ::: "memory");
        __builtin_amdgcn_s_barrier();
        cur ^= 1;
    }

    // one butterfly per row at the end
#pragma unroll
    for (int r = 0; r < 4; ++r) {
#pragma unroll
        for (int off = 1; off < 16; off <<= 1)
            lrow[r] += __shfl_xor(lrow[r], off);
    }
#pragma unroll
    for (int r = 0; r < 4; ++r) {
        const float inv = 1.0f / lrow[r];
        const int s = r0 + quad * 4 + r;
        bf16_t* dst = ao + ((size_t)(b * SS + s) * DD) + h * DH;
#pragma unroll
        for (int nt = 0; nt < 4; ++nt)
            dst[nt * 16 + l16] = (bf16_t)(o[nt][r] * inv);
    }
}
#undef PST

// ---------------------------------------------------------------------------
extern "C" void kernel_launch(void* const* d_in, const int* in_sizes, int n_in,
                              void* d_out, int out_size, void* d_ws, size_t ws_size,
                              hipStream_t stream) {
    // Select inputs BY SIZE (ordering-proof).
    const void* x_raw = nullptr;      // 8388608
    const void* w_in_raw = nullptr;   // 3145728
    const void* b_in_raw = nullptr;   // 3072
    const void* w_out_raw = nullptr;  // 1048576
    const void* b_out_raw = nullptr;  // 1024
    for (int i = 0; i < n_in; ++i) {
        switch (in_sizes[i]) {
            case 8388608: x_raw = d_in[i]; break;
            case 3145728: w_in_raw = d_in[i]; break;
            case 3072:    b_in_raw = d_in[i]; break;
            case 1048576: w_out_raw = d_in[i]; break;
            case 1024:    b_out_raw = d_in[i]; break;
            default: break;
        }
    }

    // d_out (fp32): out [4,2048,1024] | k [4,16,2048,64] | v [4,16,2048,64]
    float* outf  = (float*)d_out;
    float* koutf = outf + (size_t)MM * DD;
    float* voutf = koutf + (size_t)MM * DD;

    // bf16 scratch inside the fp32 out-section (dead before final GEMM):
    bf16_t* q_ws = (bf16_t*)d_out;
    bf16_t* k_bf = q_ws + (size_t)MM * DD;

    char* ws = (char*)d_ws;                                  // ~42 MB used
    bf16_t* xc      = (bf16_t*)(ws + 256);                   // [8192,1024]  16.78 MB
    bf16_t* ao_ws   = xc;                                    // alias: xc dead after gemm0
    bf16_t* w_in_t  = (bf16_t*)(ws + 16777472);              // [3072,1024]   6.29 MB
    bf16_t* w_out_t = (bf16_t*)(ws + 23068928);              // [1024,1024]   2.10 MB
    bf16_t* b_in_c  = (bf16_t*)(ws + 25166080);              // [3072]
    bf16_t* b_out_c = (bf16_t*)(ws + 25172224);              // [1024]
    bf16_t* v_t     = (bf16_t*)(ws + 25174272);              // [bh*64][2048] 16.78 MB

    // fused preprocessing (replaces 6 launches)
    prep<<<dim3(12304), 256, 0, stream>>>(
        x_raw, xc, w_in_raw, w_in_t, w_out_raw, w_out_t,
        b_in_raw, b_in_c, b_out_raw, b_out_c);

    // qkv = x @ w_in + b_in   (M=8192, N=3072, K=1024; 64x12 = 768 = 3x256)
    gemm256<0><<<dim3(768), 512, 0, stream>>>(
        xc, w_in_t, b_in_c, q_ws, koutf, k_bf, v_t, voutf, nullptr, 12, 3 * DD);

    // causal flash attention -> ao (bf16, in ws)
    flash_v5<<<dim3((SS / 64) * BB * HH), 256, 0, stream>>>(q_ws, k_bf, v_t, ao_ws);

    // out = ao @ w_out + b_out (overwrites q/k_bf scratch; 64x4 = 256 blocks)
    gemm256<1><<<dim3(256), 512, 0, stream>>>(
        ao_ws, w_out_t, b_out_c, nullptr, nullptr, nullptr, nullptr, nullptr,
        outf, 4, DD);
}

// Round 8
// 292.093 us; speedup vs baseline: 1.0222x; 1.0222x over previous
//
#include <hip/hip_runtime.h>
#include <hip/hip_bf16.h>
#include <math.h>

typedef __bf16 bf16_t;
typedef __bf16 bf16x2 __attribute__((ext_vector_type(2)));
typedef __bf16 bf16x4 __attribute__((ext_vector_type(4)));
typedef __bf16 bf16x8 __attribute__((ext_vector_type(8)));
typedef float floatx4 __attribute__((ext_vector_type(4)));
typedef unsigned short ushort4v __attribute__((ext_vector_type(4)));

#define AS1 __attribute__((address_space(1)))
#define AS3 __attribute__((address_space(3)))

// Problem constants
#define BB 4
#define SS 2048
#define DD 1024
#define HH 16
#define DH 64
#define MM (BB * SS)          // 8192

__device__ __forceinline__ void gld_lds16(const bf16_t* g, bf16_t* l) {
    __builtin_amdgcn_global_load_lds((const AS1 void*)g, (AS3 void*)l, 16, 0, 0);
}

// ---------------------------------------------------------------------------
// Fused preprocessing (1 kernel instead of 6; flag re-derived per block).
// ---------------------------------------------------------------------------
__global__ __launch_bounds__(256)
void prep(const void* __restrict__ x_raw, bf16_t* __restrict__ xc,
          const void* __restrict__ w_in_raw, bf16_t* __restrict__ w_in_t,
          const void* __restrict__ w_out_raw, bf16_t* __restrict__ w_out_t,
          const void* __restrict__ b_in_raw, bf16_t* __restrict__ b_in_c,
          const void* __restrict__ b_out_raw, bf16_t* __restrict__ b_out_c) {
    __shared__ bf16_t tile[32][33];
    __shared__ int sflag;
    const int tid = threadIdx.x;

    if (tid < 64) {
        const unsigned short* xs = (const unsigned short*)x_raw;
        int e0 = (xs[tid * 2] >> 7) & 0xFF;
        int e1 = (xs[tid * 2 + 1] >> 7) & 0xFF;
        int h = (e0 >= 144 ? 1 : 0) + (e1 >= 144 ? 1 : 0);
#pragma unroll
        for (int off = 1; off < 64; off <<= 1) h += __shfl_xor(h, off);
        if (tid == 0) sflag = (h >= 4) ? 1 : 0;
    }
    __syncthreads();
    const int flag = sflag;

    const int bid = blockIdx.x;
    if (bid < 8192) {
        const int i4 = (bid * 256 + tid) * 4;
        if (flag) {
            floatx4 v = ((const floatx4*)x_raw)[i4 >> 2];
            xc[i4 + 0] = (bf16_t)v[0];
            xc[i4 + 1] = (bf16_t)v[1];
            xc[i4 + 2] = (bf16_t)v[2];
            xc[i4 + 3] = (bf16_t)v[3];
        } else {
            ((ushort4v*)xc)[i4 >> 2] = ((const ushort4v*)x_raw)[i4 >> 2];
        }
    } else if (bid < 12288) {
        const void* in;
        bf16_t* out;
        int R, C, idx;
        if (bid < 11264) { in = w_in_raw; out = w_in_t; R = DD; C = 3 * DD; idx = bid - 8192; }
        else             { in = w_out_raw; out = w_out_t; R = DD; C = DD;   idx = bid - 11264; }
        const int nbx = C / 32;
        const int c0 = (idx % nbx) * 32;
        const int r0 = (idx / nbx) * 32;
        const int tx = tid & 31;
        const int ty = tid >> 5;
        if (flag) {
            const float* fin = (const float*)in;
#pragma unroll
            for (int i = 0; i < 32; i += 8)
                tile[ty + i][tx] = (bf16_t)fin[(size_t)(r0 + ty + i) * C + (c0 + tx)];
        } else {
            const bf16_t* bin = (const bf16_t*)in;
#pragma unroll
            for (int i = 0; i < 32; i += 8)
                tile[ty + i][tx] = bin[(size_t)(r0 + ty + i) * C + (c0 + tx)];
        }
        __syncthreads();
#pragma unroll
        for (int i = 0; i < 32; i += 8)
            out[(size_t)(c0 + ty + i) * R + (r0 + tx)] = tile[tx][ty + i];
    } else {
        const void* in;
        bf16_t* out;
        int i;
        if (bid < 12300) { in = b_in_raw; out = b_in_c; i = (bid - 12288) * 256 + tid; }
        else             { in = b_out_raw; out = b_out_c; i = (bid - 12300) * 256 + tid; }
        out[i] = flag ? (bf16_t)((const float*)in)[i] : ((const bf16_t*)in)[i];
    }
}

// ---------------------------------------------------------------------------
// 128x256 bf16 MFMA GEMM, BK=64, 8 waves (2M x 4N, 64x64 per wave).
// v4 schedule: one barrier/phase + ONE-PHASE-AHEAD register read pipeline.
//   phase p body: {stages} [vmcnt@p3] barrier {ds_reads for p+1} {MFMA p}
// No inline lgkm waits anywhere in the loop: the compiler's exact lgkmcnt
// counting lets the p+1 reads stay outstanding across MFMA p (r4's explicit
// lgkmcnt(0) after the barrier is what killed the earlier attempt).
// B frags: register double-buffer bfrA/bfrB, alternated by a 2-tile unrolled
// loop so every register index is compile-time (rule #20).
// vmcnt ring invariant (steady state): entering tile u, outstanding queue =
// B(u+1)x4.  p3's vmcnt(4) drains A(u+1)x2 + B(u+1)x4's predecessors exactly
// one barrier before the p3-tail reads of B(u+1)/A(u+1).  Tail: vmcnt(0) at
// u=NT-2.  Slot WAR margins >= 1 barrier + ~500cy HBM latency (audited).
// MODE 0: qkv scatter epilogue (q bf16, k fp32+bf16, v fp32+v_t bf16).
// MODE 1: plain fp32 out.  No setprio (r6 A/B: -4.4us on this GEMM).
// ---------------------------------------------------------------------------
#define MFMA8(I, AF, BR)                                                       \
    _Pragma("unroll")                                                          \
    for (int n = 0; n < 4; ++n) {                                              \
        acc[I][n] = __builtin_amdgcn_mfma_f32_16x16x32_bf16(                   \
            AF[0], BR[n][0], acc[I][n], 0, 0, 0);                              \
        acc[I][n] = __builtin_amdgcn_mfma_f32_16x16x32_bf16(                   \
            AF[1], BR[n][1], acc[I][n], 0, 0, 0);                              \
    }

#define TILE_BODY(u, CUR, NXT)                                                 \
    do {                                                                       \
        const int sa = (2 * (u) + wm) & 3;                                     \
        /* ---- p0 ---- */                                                     \
        if ((u) + 1 < NT) { stA((u) + 1, 0); stA((u) + 1, 1); }                \
        __builtin_amdgcn_s_barrier();                                          \
        readA2(Ab, sa, 1);                                                     \
        MFMA8(0, Aa, CUR);                                                     \
        /* ---- p1 ---- */                                                     \
        __builtin_amdgcn_s_barrier();                                          \
        readA2(Aa, sa, 2);                                                     \
        MFMA8(1, Ab, CUR);                                                     \
        /* ---- p2 ---- */                                                     \
        if ((u) + 2 < NT) stB((u) + 2, 0);                                     \
        __builtin_amdgcn_s_barrier();                                          \
        readA2(Ab, sa, 3);                                                     \
        MFMA8(2, Aa, CUR);                                                     \
        /* ---- p3 ---- */                                                     \
        if ((u) + 2 < NT) stB((u) + 2, 1);                                     \
        if ((u) + 1 < NT) {                                                    \
            if ((u) + 2 < NT) asm volatile("s_waitcnt vmcnt(4)" ::: "memory"); \
            else              asm volatile("s_waitcnt vmcnt(0)" ::: "memory"); \
        }                                                                      \
        __builtin_amdgcn_s_barrier();                                          \
        if ((u) + 1 < NT) {                                                    \
            readB8(NXT, (2 * ((u) + 1) + (wn >> 1)) & 3);                      \
            readA2(Aa, (2 * ((u) + 1) + wm) & 3, 0);                           \
        }                                                                      \
        MFMA8(3, Ab, CUR);                                                     \
    } while (0)

template <int MODE>
__global__ __launch_bounds__(512, 2)
void gemm256(const bf16_t* __restrict__ A, const bf16_t* __restrict__ Bt,
             const bf16_t* __restrict__ bias,
             bf16_t* __restrict__ qout, float* __restrict__ kf,
             bf16_t* __restrict__ kb, bf16_t* __restrict__ vtp,
             float* __restrict__ vf, float* __restrict__ outf,
             int nbx, int N) {
    constexpr int KK = 1024;
    constexpr int NT = KK / 64;              // 16 K-tiles
    __shared__ bf16_t Ah[4][64 * 64];        // 32 KB
    __shared__ bf16_t Bh[4][128 * 64];       // 64 KB
    const int tid = threadIdx.x;
    const int w = tid >> 6;
    const int l = tid & 63;
    const int quad = l >> 4;
    const int l16 = l & 15;
    const int wm = w & 1;                    // 2 wave-rows (64 M-rows each)
    const int wn = w >> 1;                   // 4 wave-cols (64 N-cols each)

    // XCD-bijective swizzle (gridDim.x % 8 == 0)
    const int cpx = gridDim.x >> 3;
    const int wg = (blockIdx.x & 7) * cpx + (blockIdx.x >> 3);
    const int m0 = (wg / nbx) * 128;
    const int n0 = (wg % nbx) * 256;

    // staging: row = half*64 + (tid>>3); source granule pre-swizzled so
    // LDS[row][g] = global[row][g ^ (row&7)]
    const int srow = tid >> 3;               // 0..63
    const int sg = (tid & 7) ^ (srow & 7);
    const bf16_t* ag = A + (size_t)(m0 + srow) * KK + sg * 8;
    const bf16_t* bg = Bt + (size_t)(n0 + srow) * KK + sg * 8;
    const int dst0 = w * 512;                // wave-uniform LDS base (elems)

    auto stA = [&](int u, int half) {        // 64x64 half: 1 load/thread
        gld_lds16(ag + (size_t)half * 64 * KK + u * 64,
                  &Ah[(2 * u + half) & 3][dst0]);
    };
    auto stB = [&](int u, int half) {        // 128x64 half: 2 loads/thread
        const bf16_t* g = bg + (size_t)half * 128 * KK + u * 64;
        bf16_t* s = &Bh[(2 * u + half) & 3][dst0];
        gld_lds16(g, s);
        gld_lds16(g + (size_t)64 * KK, s + 4096);
    };

    const int axor = l16 & 7;                // row&7 for all frag reads
    auto rdA = [&](int slot, int mt, int kh) -> bf16x8 {
        return *(const bf16x8*)&Ah[slot][(mt * 16 + l16) * 64 +
                                         ((((kh << 2) | quad) ^ axor) << 3)];
    };
    auto rdB = [&](int slot, int nt, int kh) -> bf16x8 {
        return *(const bf16x8*)&Bh[slot][((wn & 1) * 64 + nt * 16 + l16) * 64 +
                                         ((((kh << 2) | quad) ^ axor) << 3)];
    };

    floatx4 acc[4][4];
#pragma unroll
    for (int i = 0; i < 4; ++i)
#pragma unroll
        for (int j = 0; j < 4; ++j) {
            floatx4 z = {0.f, 0.f, 0.f, 0.f};
            acc[i][j] = z;
        }

    bf16x8 bfrA[4][2], bfrB[4][2], Aa[2], Ab[2];

    auto readA2 = [&](bf16x8 (&D)[2], int slot, int mt) {
        D[0] = rdA(slot, mt, 0);
        D[1] = rdA(slot, mt, 1);
    };
    auto readB8 = [&](bf16x8 (&D)[4][2], int slot) {
#pragma unroll
        for (int n = 0; n < 4; ++n) {
            D[n][0] = rdB(slot, n, 0);
            D[n][1] = rdB(slot, n, 1);
        }
    };

    // prologue: B(0)x4, A(0)x2, B(1)x4; demand A(0)+B(0); preload tile-0 regs
    stB(0, 0); stB(0, 1); stA(0, 0); stA(0, 1); stB(1, 0); stB(1, 1);
    asm volatile("s_waitcnt vmcnt(4)" ::: "memory");
    __builtin_amdgcn_s_barrier();
    readB8(bfrA, (wn >> 1) & 3);
    readA2(Aa, wm & 3, 0);

    for (int uu = 0; uu < NT; uu += 2) {
        TILE_BODY(uu, bfrA, bfrB);
        TILE_BODY(uu + 1, bfrB, bfrA);
    }

    // ---------------- epilogue ----------------
    // C row = m0 + wm*64 + mt*16 + quad*4 + r ; col = n0 + wn*64 + nt*16 + l16
    const int nb = n0 + wn * 64;
    const int mrow0 = m0 + wm * 64;
    float bv[4];
#pragma unroll
    for (int nt = 0; nt < 4; ++nt) bv[nt] = (float)bias[nb + nt * 16 + l16];

    if (MODE == 0) {
        const int sec = nb >> 10;            // wave-uniform: 0=q 1=k 2=v
        const int c = nb & 1023;
        const int hh = c >> 6;
        const int b = mrow0 >> 11;
        const int sb0 = mrow0 & 2047;
        if (sec == 2) {
#pragma unroll
            for (int mt = 0; mt < 4; ++mt)
#pragma unroll
                for (int nt = 0; nt < 4; ++nt) {
                    const int dcol = nt * 16 + l16;
                    const int sbase = sb0 + mt * 16 + quad * 4;
                    bf16x4 pk;
#pragma unroll
                    for (int r = 0; r < 4; ++r) {
                        const float val = acc[mt][nt][r] + bv[nt];
                        pk[r] = (bf16_t)val;
                        vf[((size_t)(b * HH + hh) * SS + sbase + r) * DH + dcol] = val;
                    }
                    *(bf16x4*)&vtp[((size_t)(b * HH + hh) * DH + dcol) * SS + sbase] = pk;
                }
        } else if (sec == 0) {
#pragma unroll
            for (int mt = 0; mt < 4; ++mt)
#pragma unroll
                for (int nt = 0; nt < 4; ++nt) {
                    const int dcol = nt * 16 + l16;
#pragma unroll
                    for (int r = 0; r < 4; ++r) {
                        const int s = sb0 + mt * 16 + quad * 4 + r;
                        qout[((size_t)(b * HH + hh) * SS + s) * DH + dcol] =
                            (bf16_t)(acc[mt][nt][r] + bv[nt]);
                    }
                }
        } else {
#pragma unroll
            for (int mt = 0; mt < 4; ++mt)
#pragma unroll
                for (int nt = 0; nt < 4; ++nt) {
                    const int dcol = nt * 16 + l16;
#pragma unroll
                    for (int r = 0; r < 4; ++r) {
                        const int s = sb0 + mt * 16 + quad * 4 + r;
                        const size_t di = ((size_t)(b * HH + hh) * SS + s) * DH + dcol;
                        const float val = acc[mt][nt][r] + bv[nt];
                        kf[di] = val;
                        kb[di] = (bf16_t)val;
                    }
                }
        }
    } else {
#pragma unroll
        for (int mt = 0; mt < 4; ++mt)
#pragma unroll
            for (int nt = 0; nt < 4; ++nt)
#pragma unroll
                for (int r = 0; r < 4; ++r) {
                    const int m = mrow0 + mt * 16 + quad * 4 + r;
                    outf[(size_t)m * N + nb + nt * 16 + l16] = acc[mt][nt][r] + bv[nt];
                }
    }
}
#undef TILE_BODY
#undef MFMA8

// ---------------------------------------------------------------------------
// Flash v5: K/V staged to LDS via global_load_lds, K double-buffered,
// XOR-swizzled reads, fixed-base softmax, XCD-pinned grid.
// + T5 setprio around QK/PV MFMA clusters (m191: +4-7% on attn).
// ---------------------------------------------------------------------------
#define PST 72   // Ps row stride (bf16 elems): 144 B -> conflict-light

// stage a 64-row x 128B tile into LDS (linear layout, source pre-swizzled)
__device__ __forceinline__ void stage_kv(const bf16_t* __restrict__ g, int rstride_e,
                                         bf16_t* l, int tid, int wave) {
#pragma unroll
    for (int half = 0; half < 2; ++half) {
        const int row = half * 32 + (tid >> 3);
        const int srcslot = (tid & 7) ^ (row & 7);
        gld_lds16(g + (size_t)row * rstride_e + srcslot * 8,
                  l + half * 2048 + wave * 512);
    }
}

// swizzled b128 fragment read: logical (row, 16B-slot s)
__device__ __forceinline__ bf16x8 ldsfrag(const bf16_t* base, int row, int s) {
    return *(const bf16x8*)&base[row * 64 + ((s ^ (row & 7)) << 3)];
}

__global__ __launch_bounds__(256)
void flash_v5(const bf16_t* __restrict__ q, const bf16_t* __restrict__ kbf,
              const bf16_t* __restrict__ vt, bf16_t* __restrict__ ao) {
    __shared__ bf16_t Ks[2][64 * 64];        // 2 x 8 KB
    __shared__ bf16_t Vs[64 * 64];           // 8 KB
    __shared__ bf16_t Ps[4][16 * PST];       // 9 KB
    const int tid = threadIdx.x;
    const int wave = tid >> 6;
    const int lane = tid & 63;
    const int quad = lane >> 4;
    const int l16 = lane & 15;

    // XCD-pinned decomposition of 2048 blocks (longest q-tiles first)
    const int linear = blockIdx.x;
    const int xcd = linear & 7;
    const int sl = linear >> 3;          // 0..255
    const int hi = sl & 7;               // head-within-XCD
    const int qt = 31 - (sl >> 3);       // longest first
    const int bh = xcd * 8 + hi;
    const int r0 = qt * 64 + wave * 16;
    const int b = bh >> 4;
    const int h = bh & 15;

    const bf16_t* qp = q + (size_t)bh * SS * DH;
    const bf16_t* kp = kbf + (size_t)bh * SS * DH;
    const bf16_t* vp = vt + (size_t)bh * DH * SS;
    bf16_t* ps = Ps[wave];

    // Q A-frags: A[m=l16][k=quad*8+j]
    bf16x8 aq0, aq1;
    {
        const bf16_t* qr = qp + (size_t)(r0 + l16) * DH + quad * 8;
        aq0 = *(const bf16x8*)qr;
        aq1 = *(const bf16x8*)(qr + 32);
    }

    floatx4 o[4];
#pragma unroll
    for (int nt = 0; nt < 4; ++nt) {
        floatx4 z = {0.f, 0.f, 0.f, 0.f};
        o[nt] = z;
    }
    float lrow[4] = {0.f, 0.f, 0.f, 0.f};

    const float c2 = 0.18033688011112042f;   // (1/sqrt(64)) * log2(e)
    const float FB = 16.0f;                  // fixed softmax base (|s*c2|<~10)
    const int nIter = qt + 1;                // j0 = 0 .. qt*64

    // prologue: stage K(0)
    stage_kv(kp, DH, Ks[0], tid, wave);
    asm volatile("s_waitcnt vmcnt(0)" ::: "memory");
    __builtin_amdgcn_s_barrier();

    int cur = 0;
    for (int it = 0; it < nIter; ++it) {
        const int j0 = it * 64;
        // issue V(j0) and K(j0+64) stages; latency covered by scores+softmax
        stage_kv(vp + j0, SS, Vs, tid, wave);
        if (it + 1 < nIter)
            stage_kv(kp + (size_t)(j0 + 64) * DH, DH, Ks[cur ^ 1], tid, wave);

        // scores from Ks[cur] (ready: barrier at end of prev iter / prologue)
        const bf16_t* Kc = Ks[cur];
        floatx4 sc[4];
        __builtin_amdgcn_s_setprio(1);
#pragma unroll
        for (int cp = 0; cp < 4; ++cp) {
            const int krow = (cp >> 1) * 32 + 2 * l16 + (cp & 1);
            const bf16x8 kf0 = ldsfrag(Kc, krow, quad);
            const bf16x8 kf1 = ldsfrag(Kc, krow, 4 + quad);
            floatx4 z = {0.f, 0.f, 0.f, 0.f};
            z = __builtin_amdgcn_mfma_f32_16x16x32_bf16(aq0, kf0, z, 0, 0, 0);
            z = __builtin_amdgcn_mfma_f32_16x16x32_bf16(aq1, kf1, z, 0, 0, 0);
            sc[cp] = z;
        }
        __builtin_amdgcn_s_setprio(0);

        // probs: p = exp2(s*c2 - FB); mask only on diagonal tile (wave-uniform)
        if (it == nIter - 1) {
#pragma unroll
            for (int r = 0; r < 4; ++r) {
                const int qi = r0 + quad * 4 + r;
                float p[4];
#pragma unroll
                for (int cp = 0; cp < 4; ++cp) {
                    const int key = j0 + (cp >> 1) * 32 + 2 * l16 + (cp & 1);
                    const float e = __builtin_amdgcn_exp2f(fmaf(sc[cp][r], c2, -FB));
                    p[cp] = (key <= qi) ? e : 0.f;
                }
                lrow[r] += (p[0] + p[1]) + (p[2] + p[3]);
                const int qrow = quad * 4 + r;
                bf16x2 w0, w1;
                w0[0] = (bf16_t)p[0]; w0[1] = (bf16_t)p[1];
                w1[0] = (bf16_t)p[2]; w1[1] = (bf16_t)p[3];
                *(bf16x2*)&ps[qrow * PST + 2 * l16] = w0;
                *(bf16x2*)&ps[qrow * PST + 32 + 2 * l16] = w1;
            }
        } else {
#pragma unroll
            for (int r = 0; r < 4; ++r) {
                float p[4];
#pragma unroll
                for (int cp = 0; cp < 4; ++cp)
                    p[cp] = __builtin_amdgcn_exp2f(fmaf(sc[cp][r], c2, -FB));
                lrow[r] += (p[0] + p[1]) + (p[2] + p[3]);
                const int qrow = quad * 4 + r;
                bf16x2 w0, w1;
                w0[0] = (bf16_t)p[0]; w0[1] = (bf16_t)p[1];
                w1[0] = (bf16_t)p[2]; w1[1] = (bf16_t)p[3];
                *(bf16x2*)&ps[qrow * PST + 2 * l16] = w0;
                *(bf16x2*)&ps[qrow * PST + 32 + 2 * l16] = w1;
            }
        }
        asm volatile("s_waitcnt lgkmcnt(0)" ::: "memory");   // wave-local Ps w->r
        bf16x8 ap0 = *(const bf16x8*)&ps[l16 * PST + quad * 8];
        bf16x8 ap1 = *(const bf16x8*)&ps[l16 * PST + 32 + quad * 8];

        // V(j0) + K(j0+64) landed (issued together at iter top); cross-wave sync
        asm volatile("s_waitcnt vmcnt(0) lgkmcnt(0)" ::: "memory");
        __builtin_amdgcn_s_barrier();

        __builtin_amdgcn_s_setprio(1);
#pragma unroll
        for (int nt = 0; nt < 4; ++nt) {
            const int vrow = nt * 16 + l16;
            const bf16x8 vf0 = ldsfrag(Vs, vrow, quad);
            const bf16x8 vf1 = ldsfrag(Vs, vrow, 4 + quad);
            o[nt] = __builtin_amdgcn_mfma_f32_16x16x32_bf16(ap0, vf0, o[nt], 0, 0, 0);
            o[nt] = __builtin_amdgcn_mfma_f32_16x16x32_bf16(ap1, vf1, o[nt], 0, 0, 0);
        }
        __builtin_amdgcn_s_setprio(0);

        // all waves done reading Vs / Ks[cur] before next-iter overwrite
        asm volatile("s_waitcnt lgkmcnt(0)" ::: "memory");
        __builtin_amdgcn_s_barrier();
        cur ^= 1;
    }

    // one butterfly per row at the end
#pragma unroll
    for (int r = 0; r < 4; ++r) {
#pragma unroll
        for (int off = 1; off < 16; off <<= 1)
            lrow[r] += __shfl_xor(lrow[r], off);
    }
#pragma unroll
    for (int r = 0; r < 4; ++r) {
        const float inv = 1.0f / lrow[r];
        const int s = r0 + quad * 4 + r;
        bf16_t* dst = ao + ((size_t)(b * SS + s) * DD) + h * DH;
#pragma unroll
        for (int nt = 0; nt < 4; ++nt)
            dst[nt * 16 + l16] = (bf16_t)(o[nt][r] * inv);
    }
}
#undef PST

// ---------------------------------------------------------------------------
extern "C" void kernel_launch(void* const* d_in, const int* in_sizes, int n_in,
                              void* d_out, int out_size, void* d_ws, size_t ws_size,
                              hipStream_t stream) {
    // Select inputs BY SIZE (ordering-proof).
    const void* x_raw = nullptr;      // 8388608
    const void* w_in_raw = nullptr;   // 3145728
    const void* b_in_raw = nullptr;   // 3072
    const void* w_out_raw = nullptr;  // 1048576
    const void* b_out_raw = nullptr;  // 1024
    for (int i = 0; i < n_in; ++i) {
        switch (in_sizes[i]) {
            case 8388608: x_raw = d_in[i]; break;
            case 3145728: w_in_raw = d_in[i]; break;
            case 3072:    b_in_raw = d_in[i]; break;
            case 1048576: w_out_raw = d_in[i]; break;
            case 1024:    b_out_raw = d_in[i]; break;
            default: break;
        }
    }

    // d_out (fp32): out [4,2048,1024] | k [4,16,2048,64] | v [4,16,2048,64]
    float* outf  = (float*)d_out;
    float* koutf = outf + (size_t)MM * DD;
    float* voutf = koutf + (size_t)MM * DD;

    // bf16 scratch inside the fp32 out-section (dead before final GEMM):
    bf16_t* q_ws = (bf16_t*)d_out;
    bf16_t* k_bf = q_ws + (size_t)MM * DD;

    char* ws = (char*)d_ws;                                  // ~42 MB used
    bf16_t* xc      = (bf16_t*)(ws + 256);                   // [8192,1024]  16.78 MB
    bf16_t* ao_ws   = xc;                                    // alias: xc dead after gemm0
    bf16_t* w_in_t  = (bf16_t*)(ws + 16777472);              // [3072,1024]   6.29 MB
    bf16_t* w_out_t = (bf16_t*)(ws + 23068928);              // [1024,1024]   2.10 MB
    bf16_t* b_in_c  = (bf16_t*)(ws + 25166080);              // [3072]
    bf16_t* b_out_c = (bf16_t*)(ws + 25172224);              // [1024]
    bf16_t* v_t     = (bf16_t*)(ws + 25174272);              // [bh*64][2048] 16.78 MB

    // fused preprocessing (replaces 6 launches)
    prep<<<dim3(12304), 256, 0, stream>>>(
        x_raw, xc, w_in_raw, w_in_t, w_out_raw, w_out_t,
        b_in_raw, b_in_c, b_out_raw, b_out_c);

    // qkv = x @ w_in + b_in   (M=8192, N=3072, K=1024; 64x12 = 768 = 3x256)
    gemm256<0><<<dim3(768), 512, 0, stream>>>(
        xc, w_in_t, b_in_c, q_ws, koutf, k_bf, v_t, voutf, nullptr, 12, 3 * DD);

    // causal flash attention -> ao (bf16, in ws)
    flash_v5<<<dim3((SS / 64) * BB * HH), 256, 0, stream>>>(q_ws, k_bf, v_t, ao_ws);

    // out = ao @ w_out + b_out (overwrites q/k_bf scratch; 64x4 = 256 blocks)
    gemm256<1><<<dim3(256), 512, 0, stream>>>(
        ao_ws, w_out_t, b_out_c, nullptr, nullptr, nullptr, nullptr, nullptr,
        outf, 4, DD);
}